// Round 1
// baseline (8338.563 us; speedup 1.0000x reference)
//
#include <hip/hip_runtime.h>
#include <stdint.h>

// ---------------------------------------------------------------------------
// Model constants
// ---------------------------------------------------------------------------
#define BATCH       64
#define SEQ_LEN     2048
#define D_MODEL     128
#define WIN         64
#define NWIN        64
#define PRED_LEN    4
#define XSTRIDE     2052   // SEQ_LEN + PRED_LEN

// ---------------------------------------------------------------------------
// Threefry-2x32 (exact jax implementation)
// ---------------------------------------------------------------------------
__device__ __forceinline__ uint32_t rotl32(uint32_t v, int d) {
    return (v << d) | (v >> (32 - d));
}

__device__ __forceinline__ void threefry2x32(uint32_t k0, uint32_t k1,
                                             uint32_t x0, uint32_t x1,
                                             uint32_t& o0, uint32_t& o1) {
    uint32_t ks0 = k0, ks1 = k1, ks2 = k0 ^ k1 ^ 0x1BD11BDAu;
    x0 += ks0; x1 += ks1;
#define TF_R(r) { x0 += x1; x1 = rotl32(x1, r); x1 ^= x0; }
    TF_R(13) TF_R(15) TF_R(26) TF_R(6)
    x0 += ks1; x1 += ks2 + 1u;
    TF_R(17) TF_R(29) TF_R(16) TF_R(24)
    x0 += ks2; x1 += ks0 + 2u;
    TF_R(13) TF_R(15) TF_R(26) TF_R(6)
    x0 += ks0; x1 += ks1 + 3u;
    TF_R(17) TF_R(29) TF_R(16) TF_R(24)
    x0 += ks1; x1 += ks2 + 4u;
    TF_R(13) TF_R(15) TF_R(26) TF_R(6)
    x0 += ks2; x1 += ks0 + 5u;
#undef TF_R
    o0 = x0; o1 = x1;
}

// ---------------------------------------------------------------------------
// Activations (fp32, ~2ulp; threshold is bf16-scale so plenty of margin)
// ---------------------------------------------------------------------------
__device__ __forceinline__ float sigf(float x) {
    return 1.f / (1.f + __expf(-x));
}
__device__ __forceinline__ float tanhf_(float x) {
    float e = __expf(2.f * x);
    return 1.f - 2.f / (e + 1.f);
}

// ---------------------------------------------------------------------------
// GRU cell helpers.  Thread layout: tid = j*2 + kh, j in [0,128) hidden unit,
// kh in {0,1} = k-half.  Thread holds Wh rows (j, j+128, j+256), cols
// [kh*64, kh*64+64) in 192 VGPRs.  h lives in LDS; lanes of one kh-group read
// identical addresses (2-way LDS broadcast, free).  Pair-combine partial sums
// with shfl_xor(1).
// ---------------------------------------------------------------------------
__device__ __forceinline__ void load_gru_weights(const float* __restrict__ Wh,
                                                 int j, int kh,
                                                 float (&wr)[64], float (&wz)[64],
                                                 float (&wn)[64]) {
    const float4* pr = (const float4*)(Wh + (size_t)(j      ) * 128 + kh * 64);
    const float4* pz = (const float4*)(Wh + (size_t)(j + 128) * 128 + kh * 64);
    const float4* pn = (const float4*)(Wh + (size_t)(j + 256) * 128 + kh * 64);
#pragma unroll
    for (int c = 0; c < 16; ++c) {
        float4 v0 = pr[c], v1 = pz[c], v2 = pn[c];
        wr[4*c+0] = v0.x; wr[4*c+1] = v0.y; wr[4*c+2] = v0.z; wr[4*c+3] = v0.w;
        wz[4*c+0] = v1.x; wz[4*c+1] = v1.y; wz[4*c+2] = v1.z; wz[4*c+3] = v1.w;
        wn[4*c+0] = v2.x; wn[4*c+1] = v2.y; wn[4*c+2] = v2.z; wn[4*c+3] = v2.w;
    }
}

__device__ __forceinline__ float gru_step(const float* hcur, int j, int kh,
                                          const float (&wr)[64], const float (&wz)[64],
                                          const float (&wn)[64],
                                          float wir, float wiz, float win,
                                          float bir, float biz, float bin,
                                          float bhr, float bhz, float bhn,
                                          float xv) {
    const float4* h4 = (const float4*)(hcur + kh * 64);
    float ar = 0.f, az = 0.f, an = 0.f;
#pragma unroll
    for (int c = 0; c < 16; ++c) {
        float4 hv = h4[c];
        ar = fmaf(wr[4*c+0], hv.x, ar);
        ar = fmaf(wr[4*c+1], hv.y, ar);
        ar = fmaf(wr[4*c+2], hv.z, ar);
        ar = fmaf(wr[4*c+3], hv.w, ar);
        az = fmaf(wz[4*c+0], hv.x, az);
        az = fmaf(wz[4*c+1], hv.y, az);
        az = fmaf(wz[4*c+2], hv.z, az);
        az = fmaf(wz[4*c+3], hv.w, az);
        an = fmaf(wn[4*c+0], hv.x, an);
        an = fmaf(wn[4*c+1], hv.y, an);
        an = fmaf(wn[4*c+2], hv.z, an);
        an = fmaf(wn[4*c+3], hv.w, an);
    }
    ar += __shfl_xor(ar, 1);
    az += __shfl_xor(az, 1);
    an += __shfl_xor(an, 1);
    float r = sigf(fmaf(xv, wir, bir) + ar + bhr);
    float z = sigf(fmaf(xv, wiz, biz) + az + bhz);
    float n = tanhf_(fmaf(xv, win, bin) + r * (an + bhn));
    float hold = hcur[j];
    return fmaf(z, hold - n, n);   // (1-z)*n + z*h
}

// ---------------------------------------------------------------------------
// K_init: copy batch_x into strided x_ext workspace
// ---------------------------------------------------------------------------
__global__ void init_kernel(const float* __restrict__ bx, float* __restrict__ xext) {
    int idx = blockIdx.x * 256 + threadIdx.x;
    if (idx < BATCH * SEQ_LEN) {
        int b = idx >> 11;
        int t = idx & 2047;
        xext[(size_t)b * XSTRIDE + t] = bx[idx];
    }
}

// ---------------------------------------------------------------------------
// K0: per-batch mean/std (fp64 accum, ddof=1), threefry starts, Q gather
// ---------------------------------------------------------------------------
__global__ void prep_kernel(const float* __restrict__ xext,
                            int* __restrict__ starts, float* __restrict__ Q,
                            int T, int stepIdx) {
    int b = blockIdx.x;
    int tid = threadIdx.x;
    const float* xb = xext + (size_t)b * XSTRIDE;

    double s = 0.0, s2 = 0.0;
    for (int t = tid; t < T; t += 256) {
        double v = (double)xb[t];
        s += v; s2 += v * v;
    }
    __shared__ double rs[256], rs2[256];
    rs[tid] = s; rs2[tid] = s2;
    __syncthreads();
    for (int off = 128; off > 0; off >>= 1) {
        if (tid < off) { rs[tid] += rs[tid + off]; rs2[tid] += rs2[tid + off]; }
        __syncthreads();
    }
    __shared__ float thr_s;
    if (tid == 0) {
        double mean = rs[0] / (double)T;
        double var = (rs2[0] - (double)T * mean * mean) / (double)(T - 1);
        if (var < 0.0) var = 0.0;
        thr_s = (float)(mean + 1.48 * sqrt(var));
    }
    __syncthreads();

    if (tid < NWIN) {
        // key_i = fold_in(key(42), stepIdx) = threefry(key=(0,42), x=(0,i))
        uint32_t ka, kb;
        threefry2x32(0u, 42u, 0u, (uint32_t)stepIdx, ka, kb);
        // split -> k1=(A0,A1), k2=(B0,B1)
        uint32_t A0, B0, A1, B1;
        threefry2x32(ka, kb, 0u, 2u, A0, B0);
        threefry2x32(ka, kb, 1u, 3u, A1, B1);

        uint32_t idx = (uint32_t)(b * NWIN + tid);
        uint32_t q = idx & 2047u;
        uint32_t h0, h1, l0, l1;
        threefry2x32(A0, A1, q, q + 2048u, h0, h1);
        threefry2x32(B0, B1, q, q + 2048u, l0, l1);
        uint32_t hi = (idx < 2048u) ? h0 : h1;
        uint32_t lo = (idx < 2048u) ? l0 : l1;

        uint32_t span = (uint32_t)(T - WIN);
        uint32_t mult = 65536u % span;
        mult = (mult * mult) % span;
        uint32_t off = ((hi % span) * mult + (lo % span)) % span;
        starts[idx] = (int)off;
        Q[idx] = (xb[off + WIN] > thr_s) ? 1.f : 0.f;
    }
}

// ---------------------------------------------------------------------------
// K1: main GRU over x[0..L) for each batch element (64 blocks).
// One block = one batch element = one CU; Wh in VGPRs.
// ---------------------------------------------------------------------------
__global__ __launch_bounds__(256, 1)
void gru_main_kernel(const float* __restrict__ xext, float* __restrict__ hstate,
                     const float* __restrict__ Wh, const float* __restrict__ Wi,
                     const float* __restrict__ bi, const float* __restrict__ bh,
                     int L, int initFlag) {
    int b = blockIdx.x;
    int tid = threadIdx.x;
    int j = tid >> 1;
    int kh = tid & 1;

    __shared__ float xsh[XSTRIDE + 4];
    __shared__ float hbuf[2][D_MODEL];

    for (int t = tid; t < L; t += 256)
        xsh[t] = xext[(size_t)b * XSTRIDE + t];
    if (tid < D_MODEL)
        hbuf[0][tid] = initFlag ? 0.f : hstate[b * D_MODEL + tid];

    float wr[64], wz[64], wn[64];
    load_gru_weights(Wh, j, kh, wr, wz, wn);
    const float wir = Wi[j], wiz = Wi[j + 128], win = Wi[j + 256];
    const float bir = bi[j], biz = bi[j + 128], bin = bi[j + 256];
    const float bhr = bh[j], bhz = bh[j + 128], bhn = bh[j + 256];

    __syncthreads();

    int cur = 0;
    for (int t = 0; t < L; ++t) {
        float hnew = gru_step(hbuf[cur], j, kh, wr, wz, wn,
                              wir, wiz, win, bir, biz, bin, bhr, bhz, bhn,
                              xsh[t]);
        hbuf[cur ^ 1][j] = hnew;  // both kh lanes write identical value
        __syncthreads();
        cur ^= 1;
    }
    if (tid < D_MODEL)
        hstate[b * D_MODEL + tid] = hbuf[cur][tid];
}

// ---------------------------------------------------------------------------
// K2: window GRUs.  Each block processes winPerBlk windows sequentially,
// loading Ww into VGPRs once.  2 blocks/CU.
// ---------------------------------------------------------------------------
__global__ __launch_bounds__(256, 2)
void gru_win_kernel(const float* __restrict__ xext, const int* __restrict__ starts,
                    float* __restrict__ S,
                    const float* __restrict__ Wh, const float* __restrict__ Wi,
                    const float* __restrict__ bi, const float* __restrict__ bh,
                    int winPerBlk) {
    int tid = threadIdx.x;
    int j = tid >> 1;
    int kh = tid & 1;

    __shared__ float wsh[WIN];
    __shared__ float hbuf[2][D_MODEL];

    float wr[64], wz[64], wn[64];
    load_gru_weights(Wh, j, kh, wr, wz, wn);
    const float wir = Wi[j], wiz = Wi[j + 128], win = Wi[j + 256];
    const float bir = bi[j], biz = bi[j + 128], bin = bi[j + 256];
    const float bhr = bh[j], bhz = bh[j + 128], bhn = bh[j + 256];

    for (int w = 0; w < winPerBlk; ++w) {
        int widx = blockIdx.x * winPerBlk + w;
        int b = widx >> 6;
        __syncthreads();  // protect wsh/hbuf reuse from previous window's readers
        int st = starts[widx];
        if (tid < WIN) wsh[tid] = xext[(size_t)b * XSTRIDE + st + tid];
        if (tid < D_MODEL) hbuf[0][tid] = 0.f;
        __syncthreads();

        int cur = 0;
        for (int t = 0; t < WIN; ++t) {
            float hnew = gru_step(hbuf[cur], j, kh, wr, wz, wn,
                                  wir, wiz, win, bir, biz, bin, bhr, bhz, bhn,
                                  wsh[t]);
            hbuf[cur ^ 1][j] = hnew;
            __syncthreads();
            cur ^= 1;
        }
        if (tid < D_MODEL)
            S[(size_t)widx * D_MODEL + tid] = hbuf[cur][tid];
    }
}

// ---------------------------------------------------------------------------
// K3: attention + output.  One wave per batch element.
// ---------------------------------------------------------------------------
__global__ void finalize_kernel(float* __restrict__ xext,
                                const float* __restrict__ hstate,
                                const float* __restrict__ S,
                                const float* __restrict__ Q,
                                const float* __restrict__ Wd, const float* __restrict__ bd,
                                const float* __restrict__ Wc, const float* __restrict__ bc,
                                float* __restrict__ out, int stepIdx) {
    int b = blockIdx.x;
    int m = threadIdx.x;  // 64 threads = 1 wave

    __shared__ float Hs[D_MODEL];
    Hs[m]      = hstate[b * D_MODEL + m];
    Hs[m + 64] = hstate[b * D_MODEL + 64 + m];
    __syncthreads();

    // logit_m = H . S[b,m,:]
    const float* Srow = S + (size_t)(b * NWIN + m) * D_MODEL;
    float acc = 0.f;
#pragma unroll
    for (int jj = 0; jj < D_MODEL; ++jj)
        acc = fmaf(Hs[jj], Srow[jj], acc);

    // softmax over 64 lanes
    float mx = acc;
#pragma unroll
    for (int d = 1; d < 64; d <<= 1) mx = fmaxf(mx, __shfl_xor(mx, d));
    float e = __expf(acc - mx);
    float se = e;
#pragma unroll
    for (int d = 1; d < 64; d <<= 1) se += __shfl_xor(se, d);
    float A = e / se;

    float qa = Q[b * NWIN + m] * A;
#pragma unroll
    for (int d = 1; d < 64; d <<= 1) qa += __shfl_xor(qa, d);

    // o = H . Wd + bd
    float po = Hs[m] * Wd[m] + Hs[m + 64] * Wd[m + 64];
#pragma unroll
    for (int d = 1; d < 64; d <<= 1) po += __shfl_xor(po, d);

    if (m == 0) {
        float o = po + bd[0];
        float u = sigf(fmaf(qa, Wc[0], bc[0]));
        float y = o + u;
        xext[(size_t)b * XSTRIDE + SEQ_LEN + stepIdx] = y;
        out[b * PRED_LEN + stepIdx] = y;                       // output 0: x[:, -4:]
        out[BATCH * PRED_LEN + b * PRED_LEN + stepIdx] = u;    // output 1: us
    }
}

// ---------------------------------------------------------------------------
// kernel_launch
// ---------------------------------------------------------------------------
extern "C" void kernel_launch(void* const* d_in, const int* in_sizes, int n_in,
                              void* d_out, int out_size, void* d_ws, size_t ws_size,
                              hipStream_t stream) {
    const float* batch_x = (const float*)d_in[0];
    const float* Wi_g = (const float*)d_in[4];
    const float* Wh_g = (const float*)d_in[5];
    const float* bi_g = (const float*)d_in[6];
    const float* bh_g = (const float*)d_in[7];
    const float* Wi_w = (const float*)d_in[8];
    const float* Wh_w = (const float*)d_in[9];
    const float* bi_w = (const float*)d_in[10];
    const float* bh_w = (const float*)d_in[11];
    const float* Wd   = (const float*)d_in[12];
    const float* bd   = (const float*)d_in[13];
    const float* Wc   = (const float*)d_in[16];
    const float* bc   = (const float*)d_in[17];
    float* out = (float*)d_out;

    // workspace layout (floats)
    float* ws = (float*)d_ws;
    float* xext   = ws;                                  // 64*2052 = 131328
    float* hstate = xext + BATCH * XSTRIDE;              // 8192
    float* Q      = hstate + BATCH * D_MODEL;            // 4096
    float* S      = Q + BATCH * NWIN;                    // 524288
    int*   starts = (int*)(S + (size_t)BATCH * NWIN * D_MODEL); // 4096 ints

    init_kernel<<<512, 256, 0, stream>>>(batch_x, xext);

    for (int i = 0; i < PRED_LEN; ++i) {
        int T = SEQ_LEN + i;                 // current x length
        int L = (i == 0) ? SEQ_LEN : (SEQ_LEN - 1 + i);  // GRU segment length

        prep_kernel<<<BATCH, 256, 0, stream>>>(xext, starts, Q, T, i);
        gru_main_kernel<<<BATCH, 256, 0, stream>>>(xext, hstate, Wh_g, Wi_g,
                                                   bi_g, bh_g, L, (i == 0) ? 1 : 0);
        gru_win_kernel<<<(BATCH * NWIN) / 8, 256, 0, stream>>>(xext, starts, S,
                                                               Wh_w, Wi_w, bi_w, bh_w, 8);
        finalize_kernel<<<BATCH, 64, 0, stream>>>(xext, hstate, S, Q,
                                                  Wd, bd, Wc, bc, out, i);
    }
}

// Round 2
// 6826.087 us; speedup vs baseline: 1.2216x; 1.2216x over previous
//
#include <hip/hip_runtime.h>
#include <stdint.h>

// ---------------------------------------------------------------------------
// Model constants
// ---------------------------------------------------------------------------
#define BATCH       64
#define SEQ_LEN     2048
#define D_MODEL     128
#define WIN         64
#define NWIN        64
#define PRED_LEN    4
#define XSTRIDE     2052   // SEQ_LEN + PRED_LEN
#define NTHREADS    512
#define MAIN_BLOCKS 64
#define WIN_BLOCKS  1024
#define WIN_PER_BLK 4      // 1024 * 4 = 4096 = BATCH*NWIN windows

// ---------------------------------------------------------------------------
// Threefry-2x32 (exact jax implementation)
// ---------------------------------------------------------------------------
__device__ __forceinline__ uint32_t rotl32(uint32_t v, int d) {
    return (v << d) | (v >> (32 - d));
}

__device__ __forceinline__ void threefry2x32(uint32_t k0, uint32_t k1,
                                             uint32_t x0, uint32_t x1,
                                             uint32_t& o0, uint32_t& o1) {
    uint32_t ks0 = k0, ks1 = k1, ks2 = k0 ^ k1 ^ 0x1BD11BDAu;
    x0 += ks0; x1 += ks1;
#define TF_R(r) { x0 += x1; x1 = rotl32(x1, r); x1 ^= x0; }
    TF_R(13) TF_R(15) TF_R(26) TF_R(6)
    x0 += ks1; x1 += ks2 + 1u;
    TF_R(17) TF_R(29) TF_R(16) TF_R(24)
    x0 += ks2; x1 += ks0 + 2u;
    TF_R(13) TF_R(15) TF_R(26) TF_R(6)
    x0 += ks0; x1 += ks1 + 3u;
    TF_R(17) TF_R(29) TF_R(16) TF_R(24)
    x0 += ks1; x1 += ks2 + 4u;
    TF_R(13) TF_R(15) TF_R(26) TF_R(6)
    x0 += ks2; x1 += ks0 + 5u;
#undef TF_R
    o0 = x0; o1 = x1;
}

// ---------------------------------------------------------------------------
// Activations
// ---------------------------------------------------------------------------
__device__ __forceinline__ float sigf(float x) {
    return 1.f / (1.f + __expf(-x));
}
__device__ __forceinline__ float tanhf_(float x) {
    float e = __expf(2.f * x);
    return 1.f - 2.f / (e + 1.f);
}

// ---------------------------------------------------------------------------
// GRU register-resident weights.  Thread layout: tid = j*4 + kq.
// j in [0,128) = hidden unit, kq in [0,4) = k-quarter (32 of 128 k-values).
// Thread holds Wh rows (j, j+128, j+256), cols [kq*32, kq*32+32) = 96 floats
// (24 float4 = 96 VGPRs).  k-groups are ROTATED by 2*kq so the 4 distinct
// LDS addresses per ds_read_b128 land in disjoint bank quads (conflict-free;
// 16 j-lanes broadcast each address).
// ---------------------------------------------------------------------------
__device__ __forceinline__ void load_weights(const float* __restrict__ Wh,
                                             int j, int kq,
                                             float4 (&wr)[8], float4 (&wz)[8],
                                             float4 (&wn)[8]) {
    const int colbase = kq * 32;
#pragma unroll
    for (int c = 0; c < 8; ++c) {
        int p = (c + 2 * kq) & 7;       // rotated physical k-group
        int col = colbase + p * 4;
        wr[c] = *(const float4*)(Wh + (size_t)(j      ) * 128 + col);
        wz[c] = *(const float4*)(Wh + (size_t)(j + 128) * 128 + col);
        wn[c] = *(const float4*)(Wh + (size_t)(j + 256) * 128 + col);
    }
}

__device__ __forceinline__ float gru_step(const float* __restrict__ hc,
                                          int j, int kq,
                                          const float4 (&wr)[8], const float4 (&wz)[8],
                                          const float4 (&wn)[8],
                                          float wir, float wiz, float win,
                                          float br,  float bz,          // bi+bh folded (r,z)
                                          float bin, float bhn,         // n kept split
                                          float xv) {
    const float4* h4 = (const float4*)hc;
    float ar = 0.f, az = 0.f, an = 0.f;
#pragma unroll
    for (int c = 0; c < 8; ++c) {
        int p = (c + 2 * kq) & 7;
        float4 hv = h4[kq * 8 + p];
        ar = fmaf(wr[c].x, hv.x, ar); ar = fmaf(wr[c].y, hv.y, ar);
        ar = fmaf(wr[c].z, hv.z, ar); ar = fmaf(wr[c].w, hv.w, ar);
        az = fmaf(wz[c].x, hv.x, az); az = fmaf(wz[c].y, hv.y, az);
        az = fmaf(wz[c].z, hv.z, az); az = fmaf(wz[c].w, hv.w, az);
        an = fmaf(wn[c].x, hv.x, an); an = fmaf(wn[c].y, hv.y, an);
        an = fmaf(wn[c].z, hv.z, an); an = fmaf(wn[c].w, hv.w, an);
    }
    ar += __shfl_xor(ar, 1); ar += __shfl_xor(ar, 2);
    az += __shfl_xor(az, 1); az += __shfl_xor(az, 2);
    an += __shfl_xor(an, 1); an += __shfl_xor(an, 2);
    float r = sigf(fmaf(xv, wir, br) + ar);
    float z = sigf(fmaf(xv, wiz, bz) + az);
    float n = tanhf_(fmaf(xv, win, bin) + r * (an + bhn));
    float hold = hc[j];
    return fmaf(z, hold - n, n);   // (1-z)*n + z*h
}

// ---------------------------------------------------------------------------
// K_init: copy batch_x into strided x_ext workspace
// ---------------------------------------------------------------------------
__global__ void init_kernel(const float* __restrict__ bx, float* __restrict__ xext) {
    int idx = blockIdx.x * 256 + threadIdx.x;
    if (idx < BATCH * SEQ_LEN) {
        int b = idx >> 11;
        int t = idx & 2047;
        xext[(size_t)b * XSTRIDE + t] = bx[idx];
    }
}

// ---------------------------------------------------------------------------
// K0: per-batch mean/std (fp64 accum, ddof=1), threefry starts, Q gather
// ---------------------------------------------------------------------------
__global__ void prep_kernel(const float* __restrict__ xext,
                            int* __restrict__ starts, float* __restrict__ Q,
                            int T, int stepIdx) {
    int b = blockIdx.x;
    int tid = threadIdx.x;
    const float* xb = xext + (size_t)b * XSTRIDE;

    double s = 0.0, s2 = 0.0;
    for (int t = tid; t < T; t += 256) {
        double v = (double)xb[t];
        s += v; s2 += v * v;
    }
    __shared__ double rs[256], rs2[256];
    rs[tid] = s; rs2[tid] = s2;
    __syncthreads();
    for (int off = 128; off > 0; off >>= 1) {
        if (tid < off) { rs[tid] += rs[tid + off]; rs2[tid] += rs2[tid + off]; }
        __syncthreads();
    }
    __shared__ float thr_s;
    if (tid == 0) {
        double mean = rs[0] / (double)T;
        double var = (rs2[0] - (double)T * mean * mean) / (double)(T - 1);
        if (var < 0.0) var = 0.0;
        thr_s = (float)(mean + 1.48 * sqrt(var));
    }
    __syncthreads();

    if (tid < NWIN) {
        // key_i = fold_in(key(42), stepIdx) = threefry(key=(0,42), x=(0,i))
        uint32_t ka, kb;
        threefry2x32(0u, 42u, 0u, (uint32_t)stepIdx, ka, kb);
        // split -> k1=(A0,A1), k2=(B0,B1)
        uint32_t A0, B0, A1, B1;
        threefry2x32(ka, kb, 0u, 2u, A0, B0);
        threefry2x32(ka, kb, 1u, 3u, A1, B1);

        uint32_t idx = (uint32_t)(b * NWIN + tid);
        uint32_t q = idx & 2047u;
        uint32_t h0, h1, l0, l1;
        threefry2x32(A0, A1, q, q + 2048u, h0, h1);
        threefry2x32(B0, B1, q, q + 2048u, l0, l1);
        uint32_t hi = (idx < 2048u) ? h0 : h1;
        uint32_t lo = (idx < 2048u) ? l0 : l1;

        uint32_t span = (uint32_t)(T - WIN);
        uint32_t mult = 65536u % span;
        mult = (mult * mult) % span;
        uint32_t off = ((hi % span) * mult + (lo % span)) % span;
        starts[idx] = (int)off;
        Q[idx] = (xb[off + WIN] > thr_s) ? 1.f : 0.f;
    }
}

// ---------------------------------------------------------------------------
// K1: FUSED main GRU (blocks 0..63) + window GRUs (blocks 64..64+1024).
// Main blocks dispatch first and own ~64 CUs for the full 2048 steps; the
// 1024 window blocks (4 windows each, 256 steps) fill the remaining CUs and
// hide entirely in the main blocks' shadow.
// ---------------------------------------------------------------------------
__global__ __launch_bounds__(NTHREADS, 2)
void gru_fused_kernel(const float* __restrict__ xext, float* __restrict__ hstate,
                      const int* __restrict__ starts, float* __restrict__ S,
                      const float* __restrict__ Wh_g, const float* __restrict__ Wi_g,
                      const float* __restrict__ bi_g, const float* __restrict__ bh_g,
                      const float* __restrict__ Wh_w, const float* __restrict__ Wi_w,
                      const float* __restrict__ bi_w, const float* __restrict__ bh_w,
                      int L, int initFlag) {
    __shared__ float xsh[XSTRIDE];
    __shared__ float hbuf[2][D_MODEL];

    int tid = threadIdx.x;
    int j = tid >> 2;
    int kq = tid & 3;

    if (blockIdx.x < MAIN_BLOCKS) {
        // ---- main GRU: one block per batch element ----
        int b = blockIdx.x;
        float4 wr[8], wz[8], wn[8];
        load_weights(Wh_g, j, kq, wr, wz, wn);
        const float wir = Wi_g[j], wiz = Wi_g[j + 128], win = Wi_g[j + 256];
        const float br  = bi_g[j] + bh_g[j];
        const float bz  = bi_g[j + 128] + bh_g[j + 128];
        const float bin = bi_g[j + 256], bhn = bh_g[j + 256];

        for (int t = tid; t < L; t += NTHREADS)
            xsh[t] = xext[(size_t)b * XSTRIDE + t];
        if (tid < D_MODEL)
            hbuf[0][tid] = initFlag ? 0.f : hstate[b * D_MODEL + tid];
        __syncthreads();

        int cur = 0;
        for (int t = 0; t < L; ++t) {
            float hnew = gru_step(hbuf[cur], j, kq, wr, wz, wn,
                                  wir, wiz, win, br, bz, bin, bhn, xsh[t]);
            if (kq == 0) hbuf[cur ^ 1][j] = hnew;
            __syncthreads();
            cur ^= 1;
        }
        if (kq == 0)
            hstate[b * D_MODEL + j] = hbuf[cur][j];
    } else {
        // ---- window GRUs: 4 windows per block, sequentially ----
        int wb = blockIdx.x - MAIN_BLOCKS;
        float4 wr[8], wz[8], wn[8];
        load_weights(Wh_w, j, kq, wr, wz, wn);
        const float wir = Wi_w[j], wiz = Wi_w[j + 128], win = Wi_w[j + 256];
        const float br  = bi_w[j] + bh_w[j];
        const float bz  = bi_w[j + 128] + bh_w[j + 128];
        const float bin = bi_w[j + 256], bhn = bh_w[j + 256];

        for (int w = 0; w < WIN_PER_BLK; ++w) {
            int widx = wb * WIN_PER_BLK + w;
            int b = widx >> 6;
            __syncthreads();   // protect xsh/hbuf reuse from previous window's readers
            int st = starts[widx];
            if (tid < WIN) xsh[tid] = xext[(size_t)b * XSTRIDE + st + tid];
            if (tid < D_MODEL) hbuf[0][tid] = 0.f;
            __syncthreads();

            int cur = 0;
            for (int t = 0; t < WIN; ++t) {
                float hnew = gru_step(hbuf[cur], j, kq, wr, wz, wn,
                                      wir, wiz, win, br, bz, bin, bhn, xsh[t]);
                if (kq == 0) hbuf[cur ^ 1][j] = hnew;
                __syncthreads();
                cur ^= 1;
            }
            if (kq == 0)
                S[(size_t)widx * D_MODEL + j] = hbuf[cur][j];
        }
    }
}

// ---------------------------------------------------------------------------
// K3: attention + output.  One wave per batch element.
// ---------------------------------------------------------------------------
__global__ void finalize_kernel(float* __restrict__ xext,
                                const float* __restrict__ hstate,
                                const float* __restrict__ S,
                                const float* __restrict__ Q,
                                const float* __restrict__ Wd, const float* __restrict__ bd,
                                const float* __restrict__ Wc, const float* __restrict__ bc,
                                float* __restrict__ out, int stepIdx) {
    int b = blockIdx.x;
    int m = threadIdx.x;  // 64 threads = 1 wave

    __shared__ float Hs[D_MODEL];
    Hs[m]      = hstate[b * D_MODEL + m];
    Hs[m + 64] = hstate[b * D_MODEL + 64 + m];
    __syncthreads();

    // logit_m = H . S[b,m,:]
    const float* Srow = S + (size_t)(b * NWIN + m) * D_MODEL;
    float acc = 0.f;
#pragma unroll
    for (int jj = 0; jj < D_MODEL; ++jj)
        acc = fmaf(Hs[jj], Srow[jj], acc);

    // softmax over 64 lanes
    float mx = acc;
#pragma unroll
    for (int d = 1; d < 64; d <<= 1) mx = fmaxf(mx, __shfl_xor(mx, d));
    float e = __expf(acc - mx);
    float se = e;
#pragma unroll
    for (int d = 1; d < 64; d <<= 1) se += __shfl_xor(se, d);
    float A = e / se;

    float qa = Q[b * NWIN + m] * A;
#pragma unroll
    for (int d = 1; d < 64; d <<= 1) qa += __shfl_xor(qa, d);

    // o = H . Wd + bd
    float po = Hs[m] * Wd[m] + Hs[m + 64] * Wd[m + 64];
#pragma unroll
    for (int d = 1; d < 64; d <<= 1) po += __shfl_xor(po, d);

    if (m == 0) {
        float o = po + bd[0];
        float u = sigf(fmaf(qa, Wc[0], bc[0]));
        float y = o + u;
        xext[(size_t)b * XSTRIDE + SEQ_LEN + stepIdx] = y;
        out[b * PRED_LEN + stepIdx] = y;                       // output 0: x[:, -4:]
        out[BATCH * PRED_LEN + b * PRED_LEN + stepIdx] = u;    // output 1: us
    }
}

// ---------------------------------------------------------------------------
// kernel_launch
// ---------------------------------------------------------------------------
extern "C" void kernel_launch(void* const* d_in, const int* in_sizes, int n_in,
                              void* d_out, int out_size, void* d_ws, size_t ws_size,
                              hipStream_t stream) {
    const float* batch_x = (const float*)d_in[0];
    const float* Wi_g = (const float*)d_in[4];
    const float* Wh_g = (const float*)d_in[5];
    const float* bi_g = (const float*)d_in[6];
    const float* bh_g = (const float*)d_in[7];
    const float* Wi_w = (const float*)d_in[8];
    const float* Wh_w = (const float*)d_in[9];
    const float* bi_w = (const float*)d_in[10];
    const float* bh_w = (const float*)d_in[11];
    const float* Wd   = (const float*)d_in[12];
    const float* bd   = (const float*)d_in[13];
    const float* Wc   = (const float*)d_in[16];
    const float* bc   = (const float*)d_in[17];
    float* out = (float*)d_out;

    // workspace layout (floats)
    float* ws = (float*)d_ws;
    float* xext   = ws;                                  // 64*2052 = 131328
    float* hstate = xext + BATCH * XSTRIDE;              // 8192
    float* Q      = hstate + BATCH * D_MODEL;            // 4096
    float* S      = Q + BATCH * NWIN;                    // 524288
    int*   starts = (int*)(S + (size_t)BATCH * NWIN * D_MODEL); // 4096 ints

    init_kernel<<<512, 256, 0, stream>>>(batch_x, xext);

    for (int i = 0; i < PRED_LEN; ++i) {
        int T = SEQ_LEN + i;                              // current x length
        int L = (i == 0) ? SEQ_LEN : (SEQ_LEN - 1 + i);   // GRU segment length

        prep_kernel<<<BATCH, 256, 0, stream>>>(xext, starts, Q, T, i);
        gru_fused_kernel<<<MAIN_BLOCKS + WIN_BLOCKS, NTHREADS, 0, stream>>>(
            xext, hstate, starts, S,
            Wh_g, Wi_g, bi_g, bh_g,
            Wh_w, Wi_w, bi_w, bh_w,
            L, (i == 0) ? 1 : 0);
        finalize_kernel<<<BATCH, 64, 0, stream>>>(xext, hstate, S, Q,
                                                  Wd, bd, Wc, bc, out, i);
    }
}

// Round 3
// 6664.449 us; speedup vs baseline: 1.2512x; 1.0243x over previous
//
#include <hip/hip_runtime.h>
#include <stdint.h>

// ---------------------------------------------------------------------------
// Model constants
// ---------------------------------------------------------------------------
#define BATCH       64
#define SEQ_LEN     2048
#define D_MODEL     128
#define WIN         64
#define NWIN        64
#define PRED_LEN    4
#define XSTRIDE     2052   // SEQ_LEN + PRED_LEN
#define NTHREADS    512
#define MAIN_BLOCKS 64
#define WIN_BLOCKS  1024
#define WIN_PER_BLK 4      // 1024 * 4 = 4096 = BATCH*NWIN windows

// Pin a value into a VGPR: breaks the def-use chain back to the load so the
// compiler cannot re-sink (rematerialize) the load into the recurrence loop.
#define PIN(x)  asm volatile("" : "+v"(x))
#define PIN4(v) do { PIN(v.x); PIN(v.y); PIN(v.z); PIN(v.w); } while (0)

// ---------------------------------------------------------------------------
// Threefry-2x32 (exact jax implementation)
// ---------------------------------------------------------------------------
__device__ __forceinline__ uint32_t rotl32(uint32_t v, int d) {
    return (v << d) | (v >> (32 - d));
}

__device__ __forceinline__ void threefry2x32(uint32_t k0, uint32_t k1,
                                             uint32_t x0, uint32_t x1,
                                             uint32_t& o0, uint32_t& o1) {
    uint32_t ks0 = k0, ks1 = k1, ks2 = k0 ^ k1 ^ 0x1BD11BDAu;
    x0 += ks0; x1 += ks1;
#define TF_R(r) { x0 += x1; x1 = rotl32(x1, r); x1 ^= x0; }
    TF_R(13) TF_R(15) TF_R(26) TF_R(6)
    x0 += ks1; x1 += ks2 + 1u;
    TF_R(17) TF_R(29) TF_R(16) TF_R(24)
    x0 += ks2; x1 += ks0 + 2u;
    TF_R(13) TF_R(15) TF_R(26) TF_R(6)
    x0 += ks0; x1 += ks1 + 3u;
    TF_R(17) TF_R(29) TF_R(16) TF_R(24)
    x0 += ks1; x1 += ks2 + 4u;
    TF_R(13) TF_R(15) TF_R(26) TF_R(6)
    x0 += ks2; x1 += ks0 + 5u;
#undef TF_R
    o0 = x0; o1 = x1;
}

// ---------------------------------------------------------------------------
// Activations
// ---------------------------------------------------------------------------
__device__ __forceinline__ float sigf(float x) {
    return 1.f / (1.f + __expf(-x));
}
__device__ __forceinline__ float tanhf_(float x) {
    float e = __expf(2.f * x);
    return 1.f - 2.f / (e + 1.f);
}

// ---------------------------------------------------------------------------
// GRU register-resident weights.  Thread layout: tid = j*4 + kq.
// j in [0,128) = hidden unit, kq in [0,4) = k-quarter (32 of 128 k-values).
// Thread holds Wh rows (j, j+128, j+256), cols [kq*32, kq*32+32) = 96 floats
// (24 float4 = 96 VGPRs), PINNED so the compiler cannot re-sink the loads
// into the recurrence loop.  k-groups are ROTATED by 2*kq so the 4 distinct
// LDS addresses per ds_read_b128 land in disjoint bank quads (conflict-free;
// 16 j-lanes broadcast each address; SQ_LDS_BANK_CONFLICT==0 measured).
// ---------------------------------------------------------------------------
__device__ __forceinline__ void load_weights(const float* __restrict__ Wh,
                                             int j, int kq,
                                             float4 (&wr)[8], float4 (&wz)[8],
                                             float4 (&wn)[8]) {
    const int colbase = kq * 32;
#pragma unroll
    for (int c = 0; c < 8; ++c) {
        int p = (c + 2 * kq) & 7;       // rotated physical k-group
        int col = colbase + p * 4;
        wr[c] = *(const float4*)(Wh + (size_t)(j      ) * 128 + col);
        wz[c] = *(const float4*)(Wh + (size_t)(j + 128) * 128 + col);
        wn[c] = *(const float4*)(Wh + (size_t)(j + 256) * 128 + col);
    }
#pragma unroll
    for (int c = 0; c < 8; ++c) {
        PIN4(wr[c]); PIN4(wz[c]); PIN4(wn[c]);
    }
}

__device__ __forceinline__ float gru_step(const float* __restrict__ hc,
                                          int j, int kq,
                                          const float4 (&wr)[8], const float4 (&wz)[8],
                                          const float4 (&wn)[8],
                                          float wir, float wiz, float win,
                                          float br,  float bz,          // bi+bh folded (r,z)
                                          float bin, float bhn,         // n kept split
                                          float xv) {
    const float4* h4 = (const float4*)hc;
    float ar = 0.f, az = 0.f, an = 0.f;
#pragma unroll
    for (int c = 0; c < 8; ++c) {
        int p = (c + 2 * kq) & 7;
        float4 hv = h4[kq * 8 + p];
        ar = fmaf(wr[c].x, hv.x, ar); ar = fmaf(wr[c].y, hv.y, ar);
        ar = fmaf(wr[c].z, hv.z, ar); ar = fmaf(wr[c].w, hv.w, ar);
        az = fmaf(wz[c].x, hv.x, az); az = fmaf(wz[c].y, hv.y, az);
        az = fmaf(wz[c].z, hv.z, az); az = fmaf(wz[c].w, hv.w, az);
        an = fmaf(wn[c].x, hv.x, an); an = fmaf(wn[c].y, hv.y, an);
        an = fmaf(wn[c].z, hv.z, an); an = fmaf(wn[c].w, hv.w, an);
    }
    ar += __shfl_xor(ar, 1); ar += __shfl_xor(ar, 2);
    az += __shfl_xor(az, 1); az += __shfl_xor(az, 2);
    an += __shfl_xor(an, 1); an += __shfl_xor(an, 2);
    float r = sigf(fmaf(xv, wir, br) + ar);
    float z = sigf(fmaf(xv, wiz, bz) + az);
    float n = tanhf_(fmaf(xv, win, bin) + r * (an + bhn));
    float hold = hc[j];
    return fmaf(z, hold - n, n);   // (1-z)*n + z*h
}

// ---------------------------------------------------------------------------
// K_init: copy batch_x into strided x_ext workspace
// ---------------------------------------------------------------------------
__global__ void init_kernel(const float* __restrict__ bx, float* __restrict__ xext) {
    int idx = blockIdx.x * 256 + threadIdx.x;
    if (idx < BATCH * SEQ_LEN) {
        int b = idx >> 11;
        int t = idx & 2047;
        xext[(size_t)b * XSTRIDE + t] = bx[idx];
    }
}

// ---------------------------------------------------------------------------
// K0: per-batch mean/std (fp64 accum, ddof=1), threefry starts, Q gather
// ---------------------------------------------------------------------------
__global__ void prep_kernel(const float* __restrict__ xext,
                            int* __restrict__ starts, float* __restrict__ Q,
                            int T, int stepIdx) {
    int b = blockIdx.x;
    int tid = threadIdx.x;
    const float* xb = xext + (size_t)b * XSTRIDE;

    double s = 0.0, s2 = 0.0;
    for (int t = tid; t < T; t += 256) {
        double v = (double)xb[t];
        s += v; s2 += v * v;
    }
    __shared__ double rs[256], rs2[256];
    rs[tid] = s; rs2[tid] = s2;
    __syncthreads();
    for (int off = 128; off > 0; off >>= 1) {
        if (tid < off) { rs[tid] += rs[tid + off]; rs2[tid] += rs2[tid + off]; }
        __syncthreads();
    }
    __shared__ float thr_s;
    if (tid == 0) {
        double mean = rs[0] / (double)T;
        double var = (rs2[0] - (double)T * mean * mean) / (double)(T - 1);
        if (var < 0.0) var = 0.0;
        thr_s = (float)(mean + 1.48 * sqrt(var));
    }
    __syncthreads();

    if (tid < NWIN) {
        // key_i = fold_in(key(42), stepIdx) = threefry(key=(0,42), x=(0,i))
        uint32_t ka, kb;
        threefry2x32(0u, 42u, 0u, (uint32_t)stepIdx, ka, kb);
        // split -> k1=(A0,A1), k2=(B0,B1)
        uint32_t A0, B0, A1, B1;
        threefry2x32(ka, kb, 0u, 2u, A0, B0);
        threefry2x32(ka, kb, 1u, 3u, A1, B1);

        uint32_t idx = (uint32_t)(b * NWIN + tid);
        uint32_t q = idx & 2047u;
        uint32_t h0, h1, l0, l1;
        threefry2x32(A0, A1, q, q + 2048u, h0, h1);
        threefry2x32(B0, B1, q, q + 2048u, l0, l1);
        uint32_t hi = (idx < 2048u) ? h0 : h1;
        uint32_t lo = (idx < 2048u) ? l0 : l1;

        uint32_t span = (uint32_t)(T - WIN);
        uint32_t mult = 65536u % span;
        mult = (mult * mult) % span;
        uint32_t off = ((hi % span) * mult + (lo % span)) % span;
        starts[idx] = (int)off;
        Q[idx] = (xb[off + WIN] > thr_s) ? 1.f : 0.f;
    }
}

// ---------------------------------------------------------------------------
// K1: FUSED main GRU (blocks 0..63) + window GRUs (blocks 64..64+1024).
// Main blocks dispatch first and own ~64 CUs for the full 2048 steps; the
// 1024 window blocks (4 windows each, 256 steps) fill the remaining CUs and
// hide in the main blocks' shadow.
// ---------------------------------------------------------------------------
__global__ __launch_bounds__(NTHREADS, 2)
void gru_fused_kernel(const float* __restrict__ xext, float* __restrict__ hstate,
                      const int* __restrict__ starts, float* __restrict__ S,
                      const float* __restrict__ Wh_g, const float* __restrict__ Wi_g,
                      const float* __restrict__ bi_g, const float* __restrict__ bh_g,
                      const float* __restrict__ Wh_w, const float* __restrict__ Wi_w,
                      const float* __restrict__ bi_w, const float* __restrict__ bh_w,
                      int L, int initFlag) {
    __shared__ float xsh[XSTRIDE];
    __shared__ float hbuf[2][D_MODEL];

    int tid = threadIdx.x;
    int j = tid >> 2;
    int kq = tid & 3;

    if (blockIdx.x < MAIN_BLOCKS) {
        // ---- main GRU: one block per batch element ----
        int b = blockIdx.x;
        float4 wr[8], wz[8], wn[8];
        load_weights(Wh_g, j, kq, wr, wz, wn);
        float wir = Wi_g[j], wiz = Wi_g[j + 128], win = Wi_g[j + 256];
        float br  = bi_g[j] + bh_g[j];
        float bz  = bi_g[j + 128] + bh_g[j + 128];
        float bin = bi_g[j + 256], bhn = bh_g[j + 256];
        PIN(wir); PIN(wiz); PIN(win); PIN(br); PIN(bz); PIN(bin); PIN(bhn);

        for (int t = tid; t < L; t += NTHREADS)
            xsh[t] = xext[(size_t)b * XSTRIDE + t];
        if (tid < D_MODEL)
            hbuf[0][tid] = initFlag ? 0.f : hstate[b * D_MODEL + tid];
        __syncthreads();

        int cur = 0;
        for (int t = 0; t < L; ++t) {
            float hnew = gru_step(hbuf[cur], j, kq, wr, wz, wn,
                                  wir, wiz, win, br, bz, bin, bhn, xsh[t]);
            if (kq == 0) hbuf[cur ^ 1][j] = hnew;
            __syncthreads();
            cur ^= 1;
        }
        if (kq == 0)
            hstate[b * D_MODEL + j] = hbuf[cur][j];
    } else {
        // ---- window GRUs: 4 windows per block, sequentially ----
        int wb = blockIdx.x - MAIN_BLOCKS;
        float4 wr[8], wz[8], wn[8];
        load_weights(Wh_w, j, kq, wr, wz, wn);
        float wir = Wi_w[j], wiz = Wi_w[j + 128], win = Wi_w[j + 256];
        float br  = bi_w[j] + bh_w[j];
        float bz  = bi_w[j + 128] + bh_w[j + 128];
        float bin = bi_w[j + 256], bhn = bh_w[j + 256];
        PIN(wir); PIN(wiz); PIN(win); PIN(br); PIN(bz); PIN(bin); PIN(bhn);

        for (int w = 0; w < WIN_PER_BLK; ++w) {
            int widx = wb * WIN_PER_BLK + w;
            int b = widx >> 6;
            __syncthreads();   // protect xsh/hbuf reuse from previous window's readers
            int st = starts[widx];
            if (tid < WIN) xsh[tid] = xext[(size_t)b * XSTRIDE + st + tid];
            if (tid < D_MODEL) hbuf[0][tid] = 0.f;
            __syncthreads();

            int cur = 0;
            for (int t = 0; t < WIN; ++t) {
                float hnew = gru_step(hbuf[cur], j, kq, wr, wz, wn,
                                      wir, wiz, win, br, bz, bin, bhn, xsh[t]);
                if (kq == 0) hbuf[cur ^ 1][j] = hnew;
                __syncthreads();
                cur ^= 1;
            }
            if (kq == 0)
                S[(size_t)widx * D_MODEL + j] = hbuf[cur][j];
        }
    }
}

// ---------------------------------------------------------------------------
// K3: attention + output.  One wave per batch element.
// ---------------------------------------------------------------------------
__global__ void finalize_kernel(float* __restrict__ xext,
                                const float* __restrict__ hstate,
                                const float* __restrict__ S,
                                const float* __restrict__ Q,
                                const float* __restrict__ Wd, const float* __restrict__ bd,
                                const float* __restrict__ Wc, const float* __restrict__ bc,
                                float* __restrict__ out, int stepIdx) {
    int b = blockIdx.x;
    int m = threadIdx.x;  // 64 threads = 1 wave

    __shared__ float Hs[D_MODEL];
    Hs[m]      = hstate[b * D_MODEL + m];
    Hs[m + 64] = hstate[b * D_MODEL + 64 + m];
    __syncthreads();

    // logit_m = H . S[b,m,:]
    const float* Srow = S + (size_t)(b * NWIN + m) * D_MODEL;
    float acc = 0.f;
#pragma unroll
    for (int jj = 0; jj < D_MODEL; ++jj)
        acc = fmaf(Hs[jj], Srow[jj], acc);

    // softmax over 64 lanes
    float mx = acc;
#pragma unroll
    for (int d = 1; d < 64; d <<= 1) mx = fmaxf(mx, __shfl_xor(mx, d));
    float e = __expf(acc - mx);
    float se = e;
#pragma unroll
    for (int d = 1; d < 64; d <<= 1) se += __shfl_xor(se, d);
    float A = e / se;

    float qa = Q[b * NWIN + m] * A;
#pragma unroll
    for (int d = 1; d < 64; d <<= 1) qa += __shfl_xor(qa, d);

    // o = H . Wd + bd
    float po = Hs[m] * Wd[m] + Hs[m + 64] * Wd[m + 64];
#pragma unroll
    for (int d = 1; d < 64; d <<= 1) po += __shfl_xor(po, d);

    if (m == 0) {
        float o = po + bd[0];
        float u = sigf(fmaf(qa, Wc[0], bc[0]));
        float y = o + u;
        xext[(size_t)b * XSTRIDE + SEQ_LEN + stepIdx] = y;
        out[b * PRED_LEN + stepIdx] = y;                       // output 0: x[:, -4:]
        out[BATCH * PRED_LEN + b * PRED_LEN + stepIdx] = u;    // output 1: us
    }
}

// ---------------------------------------------------------------------------
// kernel_launch
// ---------------------------------------------------------------------------
extern "C" void kernel_launch(void* const* d_in, const int* in_sizes, int n_in,
                              void* d_out, int out_size, void* d_ws, size_t ws_size,
                              hipStream_t stream) {
    const float* batch_x = (const float*)d_in[0];
    const float* Wi_g = (const float*)d_in[4];
    const float* Wh_g = (const float*)d_in[5];
    const float* bi_g = (const float*)d_in[6];
    const float* bh_g = (const float*)d_in[7];
    const float* Wi_w = (const float*)d_in[8];
    const float* Wh_w = (const float*)d_in[9];
    const float* bi_w = (const float*)d_in[10];
    const float* bh_w = (const float*)d_in[11];
    const float* Wd   = (const float*)d_in[12];
    const float* bd   = (const float*)d_in[13];
    const float* Wc   = (const float*)d_in[16];
    const float* bc   = (const float*)d_in[17];
    float* out = (float*)d_out;

    // workspace layout (floats)
    float* ws = (float*)d_ws;
    float* xext   = ws;                                  // 64*2052 = 131328
    float* hstate = xext + BATCH * XSTRIDE;              // 8192
    float* Q      = hstate + BATCH * D_MODEL;            // 4096
    float* S      = Q + BATCH * NWIN;                    // 524288
    int*   starts = (int*)(S + (size_t)BATCH * NWIN * D_MODEL); // 4096 ints

    init_kernel<<<512, 256, 0, stream>>>(batch_x, xext);

    for (int i = 0; i < PRED_LEN; ++i) {
        int T = SEQ_LEN + i;                              // current x length
        int L = (i == 0) ? SEQ_LEN : (SEQ_LEN - 1 + i);   // GRU segment length

        prep_kernel<<<BATCH, 256, 0, stream>>>(xext, starts, Q, T, i);
        gru_fused_kernel<<<MAIN_BLOCKS + WIN_BLOCKS, NTHREADS, 0, stream>>>(
            xext, hstate, starts, S,
            Wh_g, Wi_g, bi_g, bh_g,
            Wh_w, Wi_w, bi_w, bh_w,
            L, (i == 0) ? 1 : 0);
        finalize_kernel<<<BATCH, 64, 0, stream>>>(xext, hstate, S, Q,
                                                  Wd, bd, Wc, bc, out, i);
    }
}

// Round 4
// 5224.697 us; speedup vs baseline: 1.5960x; 1.2756x over previous
//
#include <hip/hip_runtime.h>
#include <stdint.h>

// ---------------------------------------------------------------------------
// Model constants
// ---------------------------------------------------------------------------
#define BATCH       64
#define SEQ_LEN     2048
#define D_MODEL     128
#define WIN         64
#define NWIN        64
#define PRED_LEN    4
#define XSTRIDE     2052   // SEQ_LEN + PRED_LEN
#define NTHREADS    512
#define MAIN_BLOCKS 64
#define WIN_BLOCKS  2048
#define WIN_PER_BLK 2      // 2048 * 2 = 4096 = BATCH*NWIN windows

// Pin a value into a VGPR (insurance; primary fix is pointer laundering).
#define PIN(x)  asm volatile("" : "+v"(x))
#define PIN4(v) do { PIN(v.x); PIN(v.y); PIN(v.z); PIN(v.w); } while (0)

// Launder a pointer: the compiler can no longer prove loads through it are
// invariant, so it CANNOT rematerialize/sink those loads across the
// __syncthreads() inside the recurrence loop.  This forces the loaded
// weights to stay live in VGPRs (budget 256 via launch_bounds, demand ~150).
__device__ __forceinline__ const float* launder(const float* p) {
    uintptr_t v = (uintptr_t)p;
    asm volatile("" : "+s"(v));
    return (const float*)v;
}

// ---------------------------------------------------------------------------
// Threefry-2x32 (exact jax implementation)
// ---------------------------------------------------------------------------
__device__ __forceinline__ uint32_t rotl32(uint32_t v, int d) {
    return (v << d) | (v >> (32 - d));
}

__device__ __forceinline__ void threefry2x32(uint32_t k0, uint32_t k1,
                                             uint32_t x0, uint32_t x1,
                                             uint32_t& o0, uint32_t& o1) {
    uint32_t ks0 = k0, ks1 = k1, ks2 = k0 ^ k1 ^ 0x1BD11BDAu;
    x0 += ks0; x1 += ks1;
#define TF_R(r) { x0 += x1; x1 = rotl32(x1, r); x1 ^= x0; }
    TF_R(13) TF_R(15) TF_R(26) TF_R(6)
    x0 += ks1; x1 += ks2 + 1u;
    TF_R(17) TF_R(29) TF_R(16) TF_R(24)
    x0 += ks2; x1 += ks0 + 2u;
    TF_R(13) TF_R(15) TF_R(26) TF_R(6)
    x0 += ks0; x1 += ks1 + 3u;
    TF_R(17) TF_R(29) TF_R(16) TF_R(24)
    x0 += ks1; x1 += ks2 + 4u;
    TF_R(13) TF_R(15) TF_R(26) TF_R(6)
    x0 += ks2; x1 += ks0 + 5u;
#undef TF_R
    o0 = x0; o1 = x1;
}

// ---------------------------------------------------------------------------
// Activations
// ---------------------------------------------------------------------------
__device__ __forceinline__ float sigf(float x) {
    return 1.f / (1.f + __expf(-x));
}
__device__ __forceinline__ float tanhf_(float x) {
    float e = __expf(2.f * x);
    return 1.f - 2.f / (e + 1.f);
}

// ---------------------------------------------------------------------------
// K_init: copy batch_x into strided x_ext workspace
// ---------------------------------------------------------------------------
__global__ void init_kernel(const float* __restrict__ bx, float* __restrict__ xext) {
    int idx = blockIdx.x * 256 + threadIdx.x;
    if (idx < BATCH * SEQ_LEN) {
        int b = idx >> 11;
        int t = idx & 2047;
        xext[(size_t)b * XSTRIDE + t] = bx[idx];
    }
}

// ---------------------------------------------------------------------------
// K0: per-batch mean/std (fp64 accum, ddof=1), threefry starts, Q gather
// ---------------------------------------------------------------------------
__global__ void prep_kernel(const float* __restrict__ xext,
                            int* __restrict__ starts, float* __restrict__ Q,
                            int T, int stepIdx) {
    int b = blockIdx.x;
    int tid = threadIdx.x;
    const float* xb = xext + (size_t)b * XSTRIDE;

    double s = 0.0, s2 = 0.0;
    for (int t = tid; t < T; t += 256) {
        double v = (double)xb[t];
        s += v; s2 += v * v;
    }
    __shared__ double rs[256], rs2[256];
    rs[tid] = s; rs2[tid] = s2;
    __syncthreads();
    for (int off = 128; off > 0; off >>= 1) {
        if (tid < off) { rs[tid] += rs[tid + off]; rs2[tid] += rs2[tid + off]; }
        __syncthreads();
    }
    __shared__ float thr_s;
    if (tid == 0) {
        double mean = rs[0] / (double)T;
        double var = (rs2[0] - (double)T * mean * mean) / (double)(T - 1);
        if (var < 0.0) var = 0.0;
        thr_s = (float)(mean + 1.48 * sqrt(var));
    }
    __syncthreads();

    if (tid < NWIN) {
        // key_i = fold_in(key(42), stepIdx) = threefry(key=(0,42), x=(0,i))
        uint32_t ka, kb;
        threefry2x32(0u, 42u, 0u, (uint32_t)stepIdx, ka, kb);
        // split -> k1=(A0,A1), k2=(B0,B1)
        uint32_t A0, B0, A1, B1;
        threefry2x32(ka, kb, 0u, 2u, A0, B0);
        threefry2x32(ka, kb, 1u, 3u, A1, B1);

        uint32_t idx = (uint32_t)(b * NWIN + tid);
        uint32_t q = idx & 2047u;
        uint32_t h0, h1, l0, l1;
        threefry2x32(A0, A1, q, q + 2048u, h0, h1);
        threefry2x32(B0, B1, q, q + 2048u, l0, l1);
        uint32_t hi = (idx < 2048u) ? h0 : h1;
        uint32_t lo = (idx < 2048u) ? l0 : l1;

        uint32_t span = (uint32_t)(T - WIN);
        uint32_t mult = 65536u % span;
        mult = (mult * mult) % span;
        uint32_t off = ((hi % span) * mult + (lo % span)) % span;
        starts[idx] = (int)off;
        Q[idx] = (xb[off + WIN] > thr_s) ? 1.f : 0.f;
    }
}

// ---------------------------------------------------------------------------
// K1: FUSED main GRU (blocks 0..63) + window GRUs (remaining blocks).
// Thread layout: tid = j*4 + kq; j in [0,128) hidden unit, kq in [0,4)
// k-quarter.  Thread holds Wh rows (j, j+128, j+256), cols
// [kq*32, kq*32+32) = 96 floats register-resident (pointer laundered so the
// compiler cannot re-sink the loads into the loop).  k-groups ROTATED by
// 2*kq -> the 4 distinct LDS addresses per ds_read_b128 hit disjoint bank
// quads (SQ_LDS_BANK_CONFLICT==0 measured).  t-loop unrolled by 2 so the
// h double-buffer flip is a compile-time offset:512 immediate.  Own h[j]
// ("hold") carried in a register, not re-read from LDS.
// ---------------------------------------------------------------------------

// One GRU step: reads h from hp[c] + OFF (LDS), writes new h[j] to WP.
#define GSTEP(OFF, WP, XV)                                                  \
    do {                                                                    \
        float xv_ = (XV);                                                   \
        float ar = 0.f, az = 0.f, an = 0.f;                                 \
        _Pragma("unroll")                                                   \
        for (int c = 0; c < 8; ++c) {                                       \
            float4 hv = *(const float4*)(hp[c] + (OFF));                    \
            ar = fmaf(wr[c].x, hv.x, ar); ar = fmaf(wr[c].y, hv.y, ar);     \
            ar = fmaf(wr[c].z, hv.z, ar); ar = fmaf(wr[c].w, hv.w, ar);     \
            az = fmaf(wz[c].x, hv.x, az); az = fmaf(wz[c].y, hv.y, az);     \
            az = fmaf(wz[c].z, hv.z, az); az = fmaf(wz[c].w, hv.w, az);     \
            an = fmaf(wn[c].x, hv.x, an); an = fmaf(wn[c].y, hv.y, an);     \
            an = fmaf(wn[c].z, hv.z, an); an = fmaf(wn[c].w, hv.w, an);     \
        }                                                                   \
        ar += __shfl_xor(ar, 1); ar += __shfl_xor(ar, 2);                   \
        az += __shfl_xor(az, 1); az += __shfl_xor(az, 2);                   \
        an += __shfl_xor(an, 1); an += __shfl_xor(an, 2);                   \
        float r = sigf(fmaf(xv_, wir, br) + ar);                            \
        float z = sigf(fmaf(xv_, wiz, bz) + az);                            \
        float n = tanhf_(fmaf(xv_, win, bin) + r * (an + bhn));             \
        hold = fmaf(z, hold - n, n);                                        \
        if (kq == 0) *(WP) = hold;                                          \
        __syncthreads();                                                    \
    } while (0)

__global__ __launch_bounds__(NTHREADS, 2)
void gru_fused_kernel(const float* __restrict__ xext, float* __restrict__ hstate,
                      const int* __restrict__ starts, float* __restrict__ S,
                      const float* Wh_g_, const float* Wi_g_,
                      const float* bi_g_, const float* bh_g_,
                      const float* Wh_w_, const float* Wi_w_,
                      const float* bi_w_, const float* bh_w_,
                      int L, int initFlag) {
    __shared__ float xsh[XSTRIDE];
    __shared__ float hbuf[2][D_MODEL];   // buf1 = buf0 + 512 bytes

    const int tid = threadIdx.x;
    const int j = tid >> 2;
    const int kq = tid & 3;
    const bool isMain = (blockIdx.x < MAIN_BLOCKS);

    // ---- select & launder weight pointers ----
    const float* Wh = launder(isMain ? Wh_g_ : Wh_w_);
    const float* Wi = launder(isMain ? Wi_g_ : Wi_w_);
    const float* bi = launder(isMain ? bi_g_ : bi_w_);
    const float* bh = launder(isMain ? bh_g_ : bh_w_);

    // ---- load weights into registers (rotated k-groups) ----
    float4 wr[8], wz[8], wn[8];
    const int colbase = kq * 32;
#pragma unroll
    for (int c = 0; c < 8; ++c) {
        int p = (c + 2 * kq) & 7;
        int col = colbase + p * 4;
        wr[c] = *(const float4*)(Wh + (size_t)(j      ) * 128 + col);
        wz[c] = *(const float4*)(Wh + (size_t)(j + 128) * 128 + col);
        wn[c] = *(const float4*)(Wh + (size_t)(j + 256) * 128 + col);
    }
#pragma unroll
    for (int c = 0; c < 8; ++c) { PIN4(wr[c]); PIN4(wz[c]); PIN4(wn[c]); }

    float wir = Wi[j], wiz = Wi[j + 128], win = Wi[j + 256];
    float br  = bi[j] + bh[j];
    float bz  = bi[j + 128] + bh[j + 128];
    float bin = bi[j + 256], bhn = bh[j + 256];
    PIN(wir); PIN(wiz); PIN(win); PIN(br); PIN(bz); PIN(bin); PIN(bhn);

    // ---- per-thread LDS read pointers (computed once; buf1 via +512 imm) ----
    const char* hp[8];
#pragma unroll
    for (int c = 0; c < 8; ++c) {
        int p = (c + 2 * kq) & 7;
        hp[c] = (const char*)&hbuf[0][(kq * 8 + p) * 4];
    }
    float* wp1 = &hbuf[1][j];   // written by even steps (read buf0)
    float* wp0 = &hbuf[0][j];   // written by odd steps  (read buf1)

    if (isMain) {
        // ---- main GRU: one block per batch element ----
        const int b = blockIdx.x;
        for (int t = tid; t < L; t += NTHREADS)
            xsh[t] = xext[(size_t)b * XSTRIDE + t];
        float h0 = 0.f;
        if (!initFlag) h0 = hstate[b * D_MODEL + j];
        if (tid < D_MODEL)
            hbuf[0][tid] = initFlag ? 0.f : hstate[b * D_MODEL + tid];
        float hold = h0;
        __syncthreads();

        int t = 0;
        for (; t + 1 < L; t += 2) {
            GSTEP(0,   wp1, xsh[t]);
            GSTEP(512, wp0, xsh[t + 1]);
        }
        if (t < L) GSTEP(0, wp1, xsh[t]);
        if (kq == 0) hstate[b * D_MODEL + j] = hold;
    } else {
        // ---- window GRUs: WIN_PER_BLK windows per block, sequentially ----
        const int wb = blockIdx.x - MAIN_BLOCKS;
        for (int w = 0; w < WIN_PER_BLK; ++w) {
            int widx = wb * WIN_PER_BLK + w;
            int b = widx >> 6;
            int st = starts[widx];
            if (tid < WIN) xsh[tid] = xext[(size_t)b * XSTRIDE + st + tid];
            if (tid < D_MODEL) hbuf[0][tid] = 0.f;
            float hold = 0.f;
            __syncthreads();

#pragma unroll 1
            for (int t = 0; t < WIN; t += 2) {
                GSTEP(0,   wp1, xsh[t]);
                GSTEP(512, wp0, xsh[t + 1]);
            }
            if (kq == 0) S[(size_t)widx * D_MODEL + j] = hold;
            __syncthreads();   // before next window rewrites xsh/hbuf
        }
    }
}

// ---------------------------------------------------------------------------
// K3: attention + output.  One wave per batch element.
// ---------------------------------------------------------------------------
__global__ void finalize_kernel(float* __restrict__ xext,
                                const float* __restrict__ hstate,
                                const float* __restrict__ S,
                                const float* __restrict__ Q,
                                const float* __restrict__ Wd, const float* __restrict__ bd,
                                const float* __restrict__ Wc, const float* __restrict__ bc,
                                float* __restrict__ out, int stepIdx) {
    int b = blockIdx.x;
    int m = threadIdx.x;  // 64 threads = 1 wave

    __shared__ float Hs[D_MODEL];
    Hs[m]      = hstate[b * D_MODEL + m];
    Hs[m + 64] = hstate[b * D_MODEL + 64 + m];
    __syncthreads();

    // logit_m = H . S[b,m,:]
    const float* Srow = S + (size_t)(b * NWIN + m) * D_MODEL;
    float acc = 0.f;
#pragma unroll
    for (int jj = 0; jj < D_MODEL; ++jj)
        acc = fmaf(Hs[jj], Srow[jj], acc);

    // softmax over 64 lanes
    float mx = acc;
#pragma unroll
    for (int d = 1; d < 64; d <<= 1) mx = fmaxf(mx, __shfl_xor(mx, d));
    float e = __expf(acc - mx);
    float se = e;
#pragma unroll
    for (int d = 1; d < 64; d <<= 1) se += __shfl_xor(se, d);
    float A = e / se;

    float qa = Q[b * NWIN + m] * A;
#pragma unroll
    for (int d = 1; d < 64; d <<= 1) qa += __shfl_xor(qa, d);

    // o = H . Wd + bd
    float po = Hs[m] * Wd[m] + Hs[m + 64] * Wd[m + 64];
#pragma unroll
    for (int d = 1; d < 64; d <<= 1) po += __shfl_xor(po, d);

    if (m == 0) {
        float o = po + bd[0];
        float u = sigf(fmaf(qa, Wc[0], bc[0]));
        float y = o + u;
        xext[(size_t)b * XSTRIDE + SEQ_LEN + stepIdx] = y;
        out[b * PRED_LEN + stepIdx] = y;                       // output 0: x[:, -4:]
        out[BATCH * PRED_LEN + b * PRED_LEN + stepIdx] = u;    // output 1: us
    }
}

// ---------------------------------------------------------------------------
// kernel_launch
// ---------------------------------------------------------------------------
extern "C" void kernel_launch(void* const* d_in, const int* in_sizes, int n_in,
                              void* d_out, int out_size, void* d_ws, size_t ws_size,
                              hipStream_t stream) {
    const float* batch_x = (const float*)d_in[0];
    const float* Wi_g = (const float*)d_in[4];
    const float* Wh_g = (const float*)d_in[5];
    const float* bi_g = (const float*)d_in[6];
    const float* bh_g = (const float*)d_in[7];
    const float* Wi_w = (const float*)d_in[8];
    const float* Wh_w = (const float*)d_in[9];
    const float* bi_w = (const float*)d_in[10];
    const float* bh_w = (const float*)d_in[11];
    const float* Wd   = (const float*)d_in[12];
    const float* bd   = (const float*)d_in[13];
    const float* Wc   = (const float*)d_in[16];
    const float* bc   = (const float*)d_in[17];
    float* out = (float*)d_out;

    // workspace layout (floats)
    float* ws = (float*)d_ws;
    float* xext   = ws;                                  // 64*2052 = 131328
    float* hstate = xext + BATCH * XSTRIDE;              // 8192
    float* Q      = hstate + BATCH * D_MODEL;            // 4096
    float* S      = Q + BATCH * NWIN;                    // 524288
    int*   starts = (int*)(S + (size_t)BATCH * NWIN * D_MODEL); // 4096 ints

    init_kernel<<<512, 256, 0, stream>>>(batch_x, xext);

    for (int i = 0; i < PRED_LEN; ++i) {
        int T = SEQ_LEN + i;                              // current x length
        int L = (i == 0) ? SEQ_LEN : (SEQ_LEN - 1 + i);   // GRU segment length

        prep_kernel<<<BATCH, 256, 0, stream>>>(xext, starts, Q, T, i);
        gru_fused_kernel<<<MAIN_BLOCKS + WIN_BLOCKS, NTHREADS, 0, stream>>>(
            xext, hstate, starts, S,
            Wh_g, Wi_g, bi_g, bh_g,
            Wh_w, Wi_w, bi_w, bh_w,
            L, (i == 0) ? 1 : 0);
        finalize_kernel<<<BATCH, 64, 0, stream>>>(xext, hstate, S, Q,
                                                  Wd, bd, Wc, bc, out, i);
    }
}

// Round 5
// 5223.134 us; speedup vs baseline: 1.5965x; 1.0003x over previous
//
#include <hip/hip_runtime.h>
#include <stdint.h>

// ---------------------------------------------------------------------------
// Model constants
// ---------------------------------------------------------------------------
#define BATCH       64
#define SEQ_LEN     2048
#define D_MODEL     128
#define WIN         64
#define NWIN        64
#define PRED_LEN    4
#define XSTRIDE     2052   // SEQ_LEN + PRED_LEN
#define NTHREADS    512
#define MAIN_BLOCKS 64
#define WIN_BLOCKS  2048
#define WIN_PER_BLK 2      // 2048 * 2 = 4096 = BATCH*NWIN windows

// Pin a value into a VGPR (insurance; primary fix is waves_per_eu(2,2) which
// gives the allocator a 256-VGPR budget so it allocates instead of spilling).
#define PIN(x)  asm volatile("" : "+v"(x))
#define PIN4(v) do { PIN(v.x); PIN(v.y); PIN(v.z); PIN(v.w); } while (0)

// Launder a pointer: loads through it are no longer provably invariant, so
// they cannot be rematerialized/sunk across the __syncthreads() inside the
// recurrence loop.
__device__ __forceinline__ const float* launder(const float* p) {
    uintptr_t v = (uintptr_t)p;
    asm volatile("" : "+s"(v));
    return (const float*)v;
}

// ---------------------------------------------------------------------------
// Threefry-2x32 (exact jax implementation)
// ---------------------------------------------------------------------------
__device__ __forceinline__ uint32_t rotl32(uint32_t v, int d) {
    return (v << d) | (v >> (32 - d));
}

__device__ __forceinline__ void threefry2x32(uint32_t k0, uint32_t k1,
                                             uint32_t x0, uint32_t x1,
                                             uint32_t& o0, uint32_t& o1) {
    uint32_t ks0 = k0, ks1 = k1, ks2 = k0 ^ k1 ^ 0x1BD11BDAu;
    x0 += ks0; x1 += ks1;
#define TF_R(r) { x0 += x1; x1 = rotl32(x1, r); x1 ^= x0; }
    TF_R(13) TF_R(15) TF_R(26) TF_R(6)
    x0 += ks1; x1 += ks2 + 1u;
    TF_R(17) TF_R(29) TF_R(16) TF_R(24)
    x0 += ks2; x1 += ks0 + 2u;
    TF_R(13) TF_R(15) TF_R(26) TF_R(6)
    x0 += ks0; x1 += ks1 + 3u;
    TF_R(17) TF_R(29) TF_R(16) TF_R(24)
    x0 += ks1; x1 += ks2 + 4u;
    TF_R(13) TF_R(15) TF_R(26) TF_R(6)
    x0 += ks2; x1 += ks0 + 5u;
#undef TF_R
    o0 = x0; o1 = x1;
}

// ---------------------------------------------------------------------------
// Activations
// ---------------------------------------------------------------------------
__device__ __forceinline__ float sigf(float x) {
    return 1.f / (1.f + __expf(-x));
}
__device__ __forceinline__ float tanhf_(float x) {
    float e = __expf(2.f * x);
    return 1.f - 2.f / (e + 1.f);
}

// ---------------------------------------------------------------------------
// K_init: copy batch_x into strided x_ext workspace
// ---------------------------------------------------------------------------
__global__ void init_kernel(const float* __restrict__ bx, float* __restrict__ xext) {
    int idx = blockIdx.x * 256 + threadIdx.x;
    if (idx < BATCH * SEQ_LEN) {
        int b = idx >> 11;
        int t = idx & 2047;
        xext[(size_t)b * XSTRIDE + t] = bx[idx];
    }
}

// ---------------------------------------------------------------------------
// K0: per-batch mean/std (fp64 accum, ddof=1), threefry starts, Q gather
// ---------------------------------------------------------------------------
__global__ void prep_kernel(const float* __restrict__ xext,
                            int* __restrict__ starts, float* __restrict__ Q,
                            int T, int stepIdx) {
    int b = blockIdx.x;
    int tid = threadIdx.x;
    const float* xb = xext + (size_t)b * XSTRIDE;

    double s = 0.0, s2 = 0.0;
    for (int t = tid; t < T; t += 256) {
        double v = (double)xb[t];
        s += v; s2 += v * v;
    }
    __shared__ double rs[256], rs2[256];
    rs[tid] = s; rs2[tid] = s2;
    __syncthreads();
    for (int off = 128; off > 0; off >>= 1) {
        if (tid < off) { rs[tid] += rs[tid + off]; rs2[tid] += rs2[tid + off]; }
        __syncthreads();
    }
    __shared__ float thr_s;
    if (tid == 0) {
        double mean = rs[0] / (double)T;
        double var = (rs2[0] - (double)T * mean * mean) / (double)(T - 1);
        if (var < 0.0) var = 0.0;
        thr_s = (float)(mean + 1.48 * sqrt(var));
    }
    __syncthreads();

    if (tid < NWIN) {
        // key_i = fold_in(key(42), stepIdx) = threefry(key=(0,42), x=(0,i))
        uint32_t ka, kb;
        threefry2x32(0u, 42u, 0u, (uint32_t)stepIdx, ka, kb);
        // split -> k1=(A0,A1), k2=(B0,B1)
        uint32_t A0, B0, A1, B1;
        threefry2x32(ka, kb, 0u, 2u, A0, B0);
        threefry2x32(ka, kb, 1u, 3u, A1, B1);

        uint32_t idx = (uint32_t)(b * NWIN + tid);
        uint32_t q = idx & 2047u;
        uint32_t h0, h1, l0, l1;
        threefry2x32(A0, A1, q, q + 2048u, h0, h1);
        threefry2x32(B0, B1, q, q + 2048u, l0, l1);
        uint32_t hi = (idx < 2048u) ? h0 : h1;
        uint32_t lo = (idx < 2048u) ? l0 : l1;

        uint32_t span = (uint32_t)(T - WIN);
        uint32_t mult = 65536u % span;
        mult = (mult * mult) % span;
        uint32_t off = ((hi % span) * mult + (lo % span)) % span;
        starts[idx] = (int)off;
        Q[idx] = (xb[off + WIN] > thr_s) ? 1.f : 0.f;
    }
}

// ---------------------------------------------------------------------------
// K1: FUSED main GRU (blocks 0..63) + window GRUs (remaining blocks).
// Thread layout: tid = j*4 + kq; j in [0,128) hidden unit, kq in [0,4)
// k-quarter.  Thread holds Wh rows (j, j+128, j+256), cols
// [kq*32, kq*32+32) = 96 floats register-resident.  waves_per_eu(2,2)
// clamps occupancy so the allocator has a 256-VGPR budget and keeps the
// weights live instead of spilling (VGPR=72 + 34 GB scratch FETCH measured
// without it).  k-groups ROTATED by 2*kq -> the 4 distinct LDS addresses
// per ds_read_b128 hit disjoint bank quads (SQ_LDS_BANK_CONFLICT==0
// measured).  t-loop unrolled by 2 so the h double-buffer flip is a
// compile-time offset:512 immediate.  Own h[j] carried in a register.
// ---------------------------------------------------------------------------

// One GRU step: reads h from hp[c] + OFF (LDS), writes new h[j] to WP.
#define GSTEP(OFF, WP, XV)                                                  \
    do {                                                                    \
        float xv_ = (XV);                                                   \
        float ar = 0.f, az = 0.f, an = 0.f;                                 \
        _Pragma("unroll")                                                   \
        for (int c = 0; c < 8; ++c) {                                       \
            float4 hv = *(const float4*)(hp[c] + (OFF));                    \
            ar = fmaf(wr[c].x, hv.x, ar); ar = fmaf(wr[c].y, hv.y, ar);     \
            ar = fmaf(wr[c].z, hv.z, ar); ar = fmaf(wr[c].w, hv.w, ar);     \
            az = fmaf(wz[c].x, hv.x, az); az = fmaf(wz[c].y, hv.y, az);     \
            az = fmaf(wz[c].z, hv.z, az); az = fmaf(wz[c].w, hv.w, az);     \
            an = fmaf(wn[c].x, hv.x, an); an = fmaf(wn[c].y, hv.y, an);     \
            an = fmaf(wn[c].z, hv.z, an); an = fmaf(wn[c].w, hv.w, an);     \
        }                                                                   \
        ar += __shfl_xor(ar, 1); ar += __shfl_xor(ar, 2);                   \
        az += __shfl_xor(az, 1); az += __shfl_xor(az, 2);                   \
        an += __shfl_xor(an, 1); an += __shfl_xor(an, 2);                   \
        float r = sigf(fmaf(xv_, wir, br) + ar);                            \
        float z = sigf(fmaf(xv_, wiz, bz) + az);                            \
        float n = tanhf_(fmaf(xv_, win, bin) + r * (an + bhn));             \
        hold = fmaf(z, hold - n, n);                                        \
        if (kq == 0) *(WP) = hold;                                          \
        __syncthreads();                                                    \
    } while (0)

__global__ __launch_bounds__(NTHREADS, 2)
__attribute__((amdgpu_waves_per_eu(2, 2)))
void gru_fused_kernel(const float* __restrict__ xext, float* __restrict__ hstate,
                      const int* __restrict__ starts, float* __restrict__ S,
                      const float* Wh_g_, const float* Wi_g_,
                      const float* bi_g_, const float* bh_g_,
                      const float* Wh_w_, const float* Wi_w_,
                      const float* bi_w_, const float* bh_w_,
                      int L, int initFlag) {
    __shared__ float xsh[XSTRIDE];
    __shared__ float hbuf[2][D_MODEL];   // buf1 = buf0 + 512 bytes

    const int tid = threadIdx.x;
    const int j = tid >> 2;
    const int kq = tid & 3;
    const bool isMain = (blockIdx.x < MAIN_BLOCKS);

    // ---- select & launder weight pointers ----
    const float* Wh = launder(isMain ? Wh_g_ : Wh_w_);
    const float* Wi = launder(isMain ? Wi_g_ : Wi_w_);
    const float* bi = launder(isMain ? bi_g_ : bi_w_);
    const float* bh = launder(isMain ? bh_g_ : bh_w_);

    // ---- load weights into registers (rotated k-groups) ----
    float4 wr[8], wz[8], wn[8];
    const int colbase = kq * 32;
#pragma unroll
    for (int c = 0; c < 8; ++c) {
        int p = (c + 2 * kq) & 7;
        int col = colbase + p * 4;
        wr[c] = *(const float4*)(Wh + (size_t)(j      ) * 128 + col);
        wz[c] = *(const float4*)(Wh + (size_t)(j + 128) * 128 + col);
        wn[c] = *(const float4*)(Wh + (size_t)(j + 256) * 128 + col);
    }
#pragma unroll
    for (int c = 0; c < 8; ++c) { PIN4(wr[c]); PIN4(wz[c]); PIN4(wn[c]); }

    float wir = Wi[j], wiz = Wi[j + 128], win = Wi[j + 256];
    float br  = bi[j] + bh[j];
    float bz  = bi[j + 128] + bh[j + 128];
    float bin = bi[j + 256], bhn = bh[j + 256];
    PIN(wir); PIN(wiz); PIN(win); PIN(br); PIN(bz); PIN(bin); PIN(bhn);

    // ---- per-thread LDS read pointers (computed once; buf1 via +512 imm) ----
    const char* hp[8];
#pragma unroll
    for (int c = 0; c < 8; ++c) {
        int p = (c + 2 * kq) & 7;
        hp[c] = (const char*)&hbuf[0][(kq * 8 + p) * 4];
    }
    float* wp1 = &hbuf[1][j];   // written by even steps (read buf0)
    float* wp0 = &hbuf[0][j];   // written by odd steps  (read buf1)

    if (isMain) {
        // ---- main GRU: one block per batch element ----
        const int b = blockIdx.x;
        for (int t = tid; t < L; t += NTHREADS)
            xsh[t] = xext[(size_t)b * XSTRIDE + t];
        float h0 = 0.f;
        if (!initFlag) h0 = hstate[b * D_MODEL + j];
        if (tid < D_MODEL)
            hbuf[0][tid] = initFlag ? 0.f : hstate[b * D_MODEL + tid];
        float hold = h0;
        __syncthreads();

        int t = 0;
        for (; t + 1 < L; t += 2) {
            GSTEP(0,   wp1, xsh[t]);
            GSTEP(512, wp0, xsh[t + 1]);
        }
        if (t < L) GSTEP(0, wp1, xsh[t]);
        if (kq == 0) hstate[b * D_MODEL + j] = hold;
    } else {
        // ---- window GRUs: WIN_PER_BLK windows per block, sequentially ----
        const int wb = blockIdx.x - MAIN_BLOCKS;
        for (int w = 0; w < WIN_PER_BLK; ++w) {
            int widx = wb * WIN_PER_BLK + w;
            int b = widx >> 6;
            int st = starts[widx];
            if (tid < WIN) xsh[tid] = xext[(size_t)b * XSTRIDE + st + tid];
            if (tid < D_MODEL) hbuf[0][tid] = 0.f;
            float hold = 0.f;
            __syncthreads();

#pragma unroll 1
            for (int t = 0; t < WIN; t += 2) {
                GSTEP(0,   wp1, xsh[t]);
                GSTEP(512, wp0, xsh[t + 1]);
            }
            if (kq == 0) S[(size_t)widx * D_MODEL + j] = hold;
            __syncthreads();   // before next window rewrites xsh/hbuf
        }
    }
}

// ---------------------------------------------------------------------------
// K3: attention + output.  One wave per batch element.
// ---------------------------------------------------------------------------
__global__ void finalize_kernel(float* __restrict__ xext,
                                const float* __restrict__ hstate,
                                const float* __restrict__ S,
                                const float* __restrict__ Q,
                                const float* __restrict__ Wd, const float* __restrict__ bd,
                                const float* __restrict__ Wc, const float* __restrict__ bc,
                                float* __restrict__ out, int stepIdx) {
    int b = blockIdx.x;
    int m = threadIdx.x;  // 64 threads = 1 wave

    __shared__ float Hs[D_MODEL];
    Hs[m]      = hstate[b * D_MODEL + m];
    Hs[m + 64] = hstate[b * D_MODEL + 64 + m];
    __syncthreads();

    // logit_m = H . S[b,m,:]
    const float* Srow = S + (size_t)(b * NWIN + m) * D_MODEL;
    float acc = 0.f;
#pragma unroll
    for (int jj = 0; jj < D_MODEL; ++jj)
        acc = fmaf(Hs[jj], Srow[jj], acc);

    // softmax over 64 lanes
    float mx = acc;
#pragma unroll
    for (int d = 1; d < 64; d <<= 1) mx = fmaxf(mx, __shfl_xor(mx, d));
    float e = __expf(acc - mx);
    float se = e;
#pragma unroll
    for (int d = 1; d < 64; d <<= 1) se += __shfl_xor(se, d);
    float A = e / se;

    float qa = Q[b * NWIN + m] * A;
#pragma unroll
    for (int d = 1; d < 64; d <<= 1) qa += __shfl_xor(qa, d);

    // o = H . Wd + bd
    float po = Hs[m] * Wd[m] + Hs[m + 64] * Wd[m + 64];
#pragma unroll
    for (int d = 1; d < 64; d <<= 1) po += __shfl_xor(po, d);

    if (m == 0) {
        float o = po + bd[0];
        float u = sigf(fmaf(qa, Wc[0], bc[0]));
        float y = o + u;
        xext[(size_t)b * XSTRIDE + SEQ_LEN + stepIdx] = y;
        out[b * PRED_LEN + stepIdx] = y;                       // output 0: x[:, -4:]
        out[BATCH * PRED_LEN + b * PRED_LEN + stepIdx] = u;    // output 1: us
    }
}

// ---------------------------------------------------------------------------
// kernel_launch
// ---------------------------------------------------------------------------
extern "C" void kernel_launch(void* const* d_in, const int* in_sizes, int n_in,
                              void* d_out, int out_size, void* d_ws, size_t ws_size,
                              hipStream_t stream) {
    const float* batch_x = (const float*)d_in[0];
    const float* Wi_g = (const float*)d_in[4];
    const float* Wh_g = (const float*)d_in[5];
    const float* bi_g = (const float*)d_in[6];
    const float* bh_g = (const float*)d_in[7];
    const float* Wi_w = (const float*)d_in[8];
    const float* Wh_w = (const float*)d_in[9];
    const float* bi_w = (const float*)d_in[10];
    const float* bh_w = (const float*)d_in[11];
    const float* Wd   = (const float*)d_in[12];
    const float* bd   = (const float*)d_in[13];
    const float* Wc   = (const float*)d_in[16];
    const float* bc   = (const float*)d_in[17];
    float* out = (float*)d_out;

    // workspace layout (floats)
    float* ws = (float*)d_ws;
    float* xext   = ws;                                  // 64*2052 = 131328
    float* hstate = xext + BATCH * XSTRIDE;              // 8192
    float* Q      = hstate + BATCH * D_MODEL;            // 4096
    float* S      = Q + BATCH * NWIN;                    // 524288
    int*   starts = (int*)(S + (size_t)BATCH * NWIN * D_MODEL); // 4096 ints

    init_kernel<<<512, 256, 0, stream>>>(batch_x, xext);

    for (int i = 0; i < PRED_LEN; ++i) {
        int T = SEQ_LEN + i;                              // current x length
        int L = (i == 0) ? SEQ_LEN : (SEQ_LEN - 1 + i);   // GRU segment length

        prep_kernel<<<BATCH, 256, 0, stream>>>(xext, starts, Q, T, i);
        gru_fused_kernel<<<MAIN_BLOCKS + WIN_BLOCKS, NTHREADS, 0, stream>>>(
            xext, hstate, starts, S,
            Wh_g, Wi_g, bi_g, bh_g,
            Wh_w, Wi_w, bi_w, bh_w,
            L, (i == 0) ? 1 : 0);
        finalize_kernel<<<BATCH, 64, 0, stream>>>(xext, hstate, S, Q,
                                                  Wd, bd, Wc, bc, out, i);
    }
}